// Round 1
// baseline (679.325 us; speedup 1.0000x reference)
//
#include <hip/hip_runtime.h>
#include <cmath>

#define NLEV 8
#define TSZ 16384
#define PRIME 2654435761u

struct Res { int rx[NLEV]; int ry[NLEV]; };

__global__ __launch_bounds__(256) void pg_kernel(
    const float* __restrict__ x,
    const int*   __restrict__ hashidxs,
    const float* __restrict__ table,
    const float* __restrict__ w1,   // 16x32
    const float* __restrict__ b1,   // 32
    const float* __restrict__ w2,   // 32x24
    const float* __restrict__ b2,   // 24
    float* __restrict__ out,        // [mu N*8 | inv_sigma N*8 | weight N*8 | H N*16]
    int N, Res res)
{
    int i = blockIdx.x * blockDim.x + threadIdx.x;
    if (i >= N) return;

    float2 xv = ((const float2*)x)[i];
    int hv = hashidxs[i];
    const float* tb_base = table + (size_t)hv * (NLEV * TSZ * 2);

    // ---- hash encode: 8 levels, bilinear over 4 corners ----
    float H[16];
    #pragma unroll
    for (int l = 0; l < NLEV; ++l) {
        float fx = (float)res.rx[l], fy = (float)res.ry[l];
        float posx = xv.x * fx, posy = xv.y * fy;
        float p0x = floorf(posx), p0y = floorf(posy);
        float wx = posx - p0x, wy = posy - p0y;
        unsigned cx = (unsigned)p0x, cy = (unsigned)p0y;
        const float* tb = tb_base + (size_t)l * (TSZ * 2);
        unsigned hy0 = cy * PRIME;
        unsigned hy1 = (cy + 1u) * PRIME;
        unsigned i00 = ( cx        ^ hy0) & (TSZ - 1);
        unsigned i10 = ((cx + 1u)  ^ hy0) & (TSZ - 1);
        unsigned i01 = ( cx        ^ hy1) & (TSZ - 1);
        unsigned i11 = ((cx + 1u)  ^ hy1) & (TSZ - 1);
        float2 f00 = *(const float2*)(tb + 2u * i00);
        float2 f10 = *(const float2*)(tb + 2u * i10);
        float2 f01 = *(const float2*)(tb + 2u * i01);
        float2 f11 = *(const float2*)(tb + 2u * i11);
        float w00 = (1.f - wx) * (1.f - wy);
        float w10 = wx * (1.f - wy);
        float w01 = (1.f - wx) * wy;
        float w11 = wx * wy;
        H[2*l]   = fmaf(f00.x, w00, fmaf(f10.x, w10, fmaf(f01.x, w01, f11.x * w11)));
        H[2*l+1] = fmaf(f00.y, w00, fmaf(f10.y, w10, fmaf(f01.y, w01, f11.y * w11)));
    }

    // ---- layer 1: 16 -> 32, gaussian activation exp(-50*s^2) ----
    // Weight indices are compile-time constants off a uniform kernel-arg
    // pointer -> compiler emits s_load (SGPR operand in v_fma), no LDS needed.
    float h1[32];
    #pragma unroll
    for (int j = 0; j < 32; ++j) {
        float s = b1[j];
        #pragma unroll
        for (int k = 0; k < 16; ++k) s = fmaf(H[k], w1[k * 32 + j], s);
        h1[j] = __expf(-50.f * s * s);
    }

    // ---- layer 2: 32 -> 24 ----
    float raw[24];
    #pragma unroll
    for (int j = 0; j < 24; ++j) {
        float s = b2[j];
        #pragma unroll
        for (int k = 0; k < 32; ++k) s = fmaf(h1[k], w2[k * 24 + j], s);
        raw[j] = s;
    }

    // ---- heads ----
    float wt[8], mu[8], isg[8];
    #pragma unroll
    for (int g = 0; g < 8; ++g) {
        wt[g]  = __expf(raw[g]);
        mu[g]  = 1.f / (1.f + __expf(-raw[8 + g]));
        isg[g] = __expf(raw[16 + g]);
    }

    size_t N8 = (size_t)N * 8;
    float4* o;
    o = (float4*)(out) + (size_t)i * 2;
    o[0] = make_float4(mu[0], mu[1], mu[2], mu[3]);
    o[1] = make_float4(mu[4], mu[5], mu[6], mu[7]);
    o = (float4*)(out + N8) + (size_t)i * 2;
    o[0] = make_float4(isg[0], isg[1], isg[2], isg[3]);
    o[1] = make_float4(isg[4], isg[5], isg[6], isg[7]);
    o = (float4*)(out + 2 * N8) + (size_t)i * 2;
    o[0] = make_float4(wt[0], wt[1], wt[2], wt[3]);
    o[1] = make_float4(wt[4], wt[5], wt[6], wt[7]);
    o = (float4*)(out + 3 * N8) + (size_t)i * 4;
    o[0] = make_float4(H[0],  H[1],  H[2],  H[3]);
    o[1] = make_float4(H[4],  H[5],  H[6],  H[7]);
    o[2] = make_float4(H[8],  H[9],  H[10], H[11]);
    o[3] = make_float4(H[12], H[13], H[14], H[15]);
}

extern "C" void kernel_launch(void* const* d_in, const int* in_sizes, int n_in,
                              void* d_out, int out_size, void* d_ws, size_t ws_size,
                              hipStream_t stream) {
    const float* x        = (const float*)d_in[0];
    const int*   hashidxs = (const int*)  d_in[1];
    // d_in[2] = color (unused by reference computation)
    const float* table    = (const float*)d_in[3];
    const float* w1       = (const float*)d_in[4];
    const float* b1       = (const float*)d_in[5];
    const float* w2       = (const float*)d_in[6];
    const float* b2       = (const float*)d_in[7];
    float* out = (float*)d_out;
    int N = in_sizes[0] / 2;

    // Replicate numpy's _level_resolutions() double-precision op sequence
    // exactly (log/exp/pow via libm) — floor(16*bx^7) sits ~3e-15 from 1024,
    // so hardcoding a guess risks an off-by-one at the finest level.
    Res res;
    double bx = std::exp((std::log((double)1024) - std::log((double)16)) / 7.0);
    double by = std::exp((std::log((double)768)  - std::log((double)16)) / 7.0);
    for (int l = 0; l < NLEV; ++l) {
        res.rx[l] = (int)std::floor(16.0 * std::pow(bx, (double)l));
        res.ry[l] = (int)std::floor(16.0 * std::pow(by, (double)l));
    }

    dim3 block(256), grid((unsigned)((N + 255) / 256));
    hipLaunchKernelGGL(pg_kernel, grid, block, 0, stream,
                       x, hashidxs, table, w1, b1, w2, b2, out, N, res);
}